// Round 21
// baseline (177.879 us; speedup 1.0000x reference)
//
#include <hip/hip_runtime.h>
#include <hip/hip_bf16.h>
#include <stdint.h>

typedef __attribute__((ext_vector_type(8))) short short8;
typedef __attribute__((ext_vector_type(4))) short short4v;
typedef __attribute__((ext_vector_type(4))) float f32x4;
typedef __attribute__((ext_vector_type(16))) float f32x16;
typedef unsigned short u16;
typedef unsigned int u32;

#define DEV __device__ __forceinline__

constexpr int Bb = 2, Ss = 4096, Cc = 640, Hh = 8, Dd = 80;
constexpr int BS = Bb * Ss;          // 8192
constexpr int NQKV = 3 * Cc;         // 1920
constexpr int QKst = 2 * Cc;         // 1280

DEV float bf2f(u16 u) { unsigned v = ((unsigned)u) << 16; float f; __builtin_memcpy(&f, &v, 4); return f; }
DEV u16 f2bf(float f) {
    unsigned u; __builtin_memcpy(&u, &f, 4);
    u += 0x7fffu + ((u >> 16) & 1u);
    return (u16)(u >> 16);
}
DEV u32 packbf2(float a, float b) {
    float2 f2; f2.x = a; f2.y = b;
    __hip_bfloat162 h2 = __float22bfloat162_rn(f2);
    u32 r; __builtin_memcpy(&r, &h2, 4);
    return r;
}

DEV void pswapf(float &a, float &b) {
#if __has_builtin(__builtin_amdgcn_permlane32_swap)
    auto r = __builtin_amdgcn_permlane32_swap(__float_as_int(a), __float_as_int(b), false, false);
    a = __int_as_float(r[0]); b = __int_as_float(r[1]);
#else
    float sa = __shfl_xor(a, 32, 64), sb = __shfl_xor(b, 32, 64);
    bool hi = (threadIdx.x & 32) != 0;
    float na = hi ? sb : a, nb = hi ? b : sa;
    a = na; b = nb;
#endif
}

#define GLD16(gp, lp) __builtin_amdgcn_global_load_lds( \
    (const __attribute__((address_space(1))) void*)(gp), \
    (__attribute__((address_space(3))) void*)(lp), 16, 0, 0)

// ---------------------------------------------------------------------------
// Kernel A (merged): blocks [0,1600): weight transpose; rest: hs->bf16 + bias.
// ---------------------------------------------------------------------------
__global__ __launch_bounds__(256) void prep_kernel(
    const float* __restrict__ hs,
    const float* __restrict__ Wq, const float* __restrict__ Wk,
    const float* __restrict__ Wv, const float* __restrict__ Wo,
    const float* __restrict__ bq, const float* __restrict__ bk,
    const float* __restrict__ bv,
    u16* __restrict__ Xb, float* __restrict__ bcat,
    u16* __restrict__ WTqkv, u16* __restrict__ WTo)
{
    const float QS = 0.11180339887498949f * 1.4426950408889634f;
    if (blockIdx.x < 1600) {
        __shared__ float T[32][33];
        int tile = blockIdx.x;
        int wsel = tile / 400;
        int tt = tile - wsel * 400;
        int tr = tt / 20, tc = tt - (tt / 20) * 20;
        const float* W = (wsel == 0) ? Wq : (wsel == 1) ? Wk : (wsel == 2) ? Wv : Wo;
        float sc = (wsel == 0) ? QS : 1.0f;
        int r = threadIdx.x >> 3, c4 = (threadIdx.x & 7) * 4;
        float4 v = *(const float4*)(W + (size_t)(tr * 32 + r) * Cc + tc * 32 + c4);
        T[r][c4 + 0] = v.x; T[r][c4 + 1] = v.y; T[r][c4 + 2] = v.z; T[r][c4 + 3] = v.w;
        __syncthreads();
        short4v o;
#pragma unroll
        for (int j = 0; j < 4; j++) o[j] = (short)f2bf(T[c4 + j][r] * sc);
        u16* dst = (wsel < 3) ? (WTqkv + (size_t)(wsel * Cc + tc * 32 + r) * Cc + tr * 32 + c4)
                              : (WTo + (size_t)(tc * 32 + r) * Cc + tr * 32 + c4);
        *(short4v*)dst = o;
    } else {
        int tid = (blockIdx.x - 1600) * blockDim.x + threadIdx.x;
        int nthr = 2048 * blockDim.x;
        for (int i = tid; i < BS * Cc / 4; i += nthr) {
            float4 v = ((const float4*)hs)[i];
            short4v o;
            o[0] = (short)f2bf(v.x); o[1] = (short)f2bf(v.y);
            o[2] = (short)f2bf(v.z); o[3] = (short)f2bf(v.w);
            ((short4v*)Xb)[i] = o;
        }
        for (int i = tid; i < NQKV; i += nthr) {
            float v = (i < Cc) ? bq[i] * QS : (i < 2 * Cc) ? bk[i - Cc] : bv[i - 2 * Cc];
            bcat[i] = v;
        }
    }
}

// ---------------------------------------------------------------------------
// Kernel B: QKV GEMM (m97-style staging). Q,K -> QK[row][1280]; V -> VTg
// transposed + kv bits 2<->3 pre-permuted.
// ---------------------------------------------------------------------------
__global__ __launch_bounds__(256) void gemm_qkv(
    const u16* __restrict__ A, const u16* __restrict__ Bt,
    const float* __restrict__ bias, u16* __restrict__ QK,
    u16* __restrict__ VTg)
{
    __shared__ __align__(16) char gsm[32768];

    const int mBase = blockIdx.x * 128;
    const int nBase = blockIdx.y * 128;
    const int t = threadIdx.x, lane = t & 63, w = t >> 6;
    const int wr = w >> 1, wc = w & 1;
    const int l15 = lane & 15, g = lane >> 4;

    const int r0 = t >> 2, r1 = (t + 256) >> 2;
    const int cg0 = (t & 3) ^ (r0 & 3);
    const int cg1 = (t & 3) ^ (r1 & 3);
    const u16* pa0 = A + (size_t)(mBase + r0) * Cc + cg0 * 8;
    const u16* pa1 = A + (size_t)(mBase + r1) * Cc + cg1 * 8;
    const u16* pb0 = Bt + (size_t)(nBase + r0) * Cc + cg0 * 8;
    const u16* pb1 = Bt + (size_t)(nBase + r1) * Cc + cg1 * 8;

    auto stage = [&](int k0, int buf) {
        GLD16(pa0 + k0, gsm + buf * 8192 + w * 1024);
        GLD16(pa1 + k0, gsm + buf * 8192 + 4096 + w * 1024);
        GLD16(pb0 + k0, gsm + 16384 + buf * 8192 + w * 1024);
        GLD16(pb1 + k0, gsm + 16384 + buf * 8192 + 4096 + w * 1024);
    };

    stage(0, 0);
    __syncthreads();

    f32x4 acc[4][4] = {};
    const int lof = l15 * 64 + ((g ^ (l15 & 3)) << 4);
    int cur = 0;

    for (int k0 = 0; k0 < Cc; k0 += 32) {
        if (k0 + 32 < Cc) stage(k0 + 32, cur ^ 1);
        short8 af[4], bf[4];
#pragma unroll
        for (int i = 0; i < 4; i++) {
            af[i] = *(const short8*)(gsm + cur * 8192 + wr * 4096 + i * 1024 + lof);
            bf[i] = *(const short8*)(gsm + 16384 + cur * 8192 + wc * 4096 + i * 1024 + lof);
        }
#pragma unroll
        for (int mi = 0; mi < 4; mi++)
#pragma unroll
            for (int ni = 0; ni < 4; ni++)
                acc[mi][ni] = __builtin_amdgcn_mfma_f32_16x16x32_bf16(af[mi], bf[ni], acc[mi][ni], 0, 0, 0);
        __syncthreads();
        cur ^= 1;
    }

    if (nBase < 2 * Cc) {
#pragma unroll
        for (int mi = 0; mi < 4; mi++)
#pragma unroll
            for (int ni = 0; ni < 4; ni++) {
                int col = nBase + wc * 64 + ni * 16 + l15;
                float bb = bias[col];
#pragma unroll
                for (int r = 0; r < 4; r++) {
                    int row = mBase + wr * 64 + mi * 16 + g * 4 + r;
                    QK[(size_t)row * QKst + col] = f2bf(acc[mi][ni][r] + bb);
                }
            }
    } else {
        const int gp = ((g & 1) << 1) | (g >> 1);   // kv bits 2<->3 swap
#pragma unroll
        for (int mi = 0; mi < 4; mi++)
#pragma unroll
            for (int ni = 0; ni < 4; ni++) {
                int colg = nBase + wc * 64 + ni * 16 + l15;   // 1280..1919
                float bb = bias[colg];
                int vc = colg - 2 * Cc;
                int h = vc / Dd, d = vc - h * Dd;
                int row0 = mBase + wr * 64 + mi * 16 + gp * 4;
                int b = (mBase >> 12), s = row0 & 4095;
                short4v o;
#pragma unroll
                for (int r = 0; r < 4; r++) o[r] = (short)f2bf(acc[mi][ni][r] + bb);
                *(short4v*)(VTg + ((size_t)(b * Hh + h) * Dd + d) * Ss + s) = o;
            }
    }
}

// ---------------------------------------------------------------------------
// Kernel C: flash attention — LOCKED session optimum (3x confirmed 177.4-177.8
// us total): 2 kv-splits, deep-prefetch/one-barrier schedule, K AND V double-
// buffered (LDS 45056), separate simple stage lambdas (VGPR 72),
// launch_bounds(256,3). Refuted: ns=3 (R13/R17), unified stage loop (R14),
// 6-wave bound (R7), s2-lookahead T15 (R19). Remaining gap is 8-phase
// counted-vmcnt territory (inline-asm; hipcc defeats it at source level).
// ---------------------------------------------------------------------------
constexpr int OBP = 88;

__global__ __launch_bounds__(256, 3) void attn_kernel(
    const u16* __restrict__ QK, const u16* __restrict__ VTg,
    u16* __restrict__ N0, u16* __restrict__ N1,
    float* __restrict__ Mp, float* __restrict__ Lp)
{
    __shared__ __align__(16) char smem[45056];

    const int id = blockIdx.x;          // 0..1023
    const int qt = id >> 5;
    const int bh = (id & 31) >> 1;
    const int kvs = id & 1;
    const int b = bh >> 3, h = bh & 7;
    const int t = threadIdx.x, lane = t & 63, w = t >> 6;
    const int l31 = lane & 31, e = lane >> 5;

    const size_t rowBase = (size_t)b * Ss;
    const int q0 = qt * 128;
    const int kvBase = kvs * (Ss / 2);
    constexpr int NT = (Ss / 2) / 64;   // 32

    const int lq8 = lane >> 3;
    const int vcg = (lane & 7) ^ lq8;
    const u16* kg0 = QK + (rowBase + kvBase + lane) * QKst + Cc + h * Dd;
    const u16* vg0 = VTg + ((size_t)bh * Dd) * Ss + kvBase + vcg * 8;

    for (int i = t; i < 512; i += 256) {
        ((u32*)(smem + 10240 + 80 * 128))[i] = 0x3F803F80u;
        ((u32*)(smem + 22528 + 10240 + 80 * 128))[i] = 0x3F803F80u;
    }

    short8 qB[5];
    {
        const u16* qp = QK + (rowBase + q0 + w * 32 + l31) * QKst + h * Dd + e * 8;
#pragma unroll
        for (int ks = 0; ks < 5; ks++) qB[ks] = *(const short8*)(qp + ks * 16);
    }

    auto stageK = [&](int kt, int buf) {
#pragma unroll
        for (int j = 0; j < 3; j++) {
            int gi = w + 4 * j;
            if (gi < 10)
                GLD16(kg0 + (size_t)kt * 64 * QKst + gi * 8,
                      smem + buf * 22528 + gi * 1024);
        }
    };
    auto stageV = [&](int kt, int buf) {
#pragma unroll
        for (int j = 0; j < 3; j++) {
            int gi = w + 4 * j;
            if (gi < 10)
                GLD16(vg0 + (size_t)(gi * 8 + lq8) * Ss + kt * 64,
                      smem + buf * 22528 + 10240 + gi * 1024);
        }
    };

    stageK(0, 0);
    stageV(0, 0);
    stageK(1, 1);
    stageV(1, 1);
    __syncthreads();   // tiles 0,1 + ones rows in LDS

    float mrow = -1e30f;
    f32x16 oacc[3] = {};
    const int csl_base = l31 & 7;

    for (int kt = 0; kt < NT; ++kt) {
        const char* kb = smem + (kt & 1) * 22528;
        const char* vb = kb + 10240;

        f32x16 s2[2];
        __builtin_amdgcn_s_setprio(1);
#pragma unroll
        for (int n = 0; n < 2; n++) {
            f32x16 a = {};
#pragma unroll
            for (int ks = 0; ks < 5; ks++) {
                short8 kf = *(const short8*)(kb + ((2 * ks + e) * 64 + n * 32 + l31) * 16);
                a = __builtin_amdgcn_mfma_f32_32x32x16_bf16(kf, qB[ks], a, 0, 0, 0);
            }
            s2[n] = a;
        }
        __builtin_amdgcn_s_setprio(0);

#define SV(j) ((j) < 16 ? s2[0][(j)] : s2[1][(j) - 16])
        float tt[11];
#pragma unroll
        for (int i = 0; i < 10; i++)
            tt[i] = fmaxf(fmaxf(SV(3 * i), SV(3 * i + 1)), SV(3 * i + 2));
        tt[10] = fmaxf(SV(30), SV(31));
#undef SV
        float u0 = fmaxf(fmaxf(tt[0], tt[1]), tt[2]);
        float u1 = fmaxf(fmaxf(tt[3], tt[4]), tt[5]);
        float u2 = fmaxf(fmaxf(tt[6], tt[7]), tt[8]);
        float u3 = fmaxf(tt[9], tt[10]);
        float vm = fmaxf(fmaxf(u0, u1), fmaxf(u2, u3));
        { float va = vm, vb2 = vm; pswapf(va, vb2); vm = fmaxf(va, vb2); }

        if (__any(vm > mrow + 8.0f)) {   // defer-max; l rescales inside oacc[2]
            float mnew = fmaxf(mrow, vm);
            float al = __builtin_amdgcn_exp2f(mrow - mnew);
            mrow = mnew;
#pragma unroll
            for (int n = 0; n < 3; n++)
#pragma unroll
                for (int r = 0; r < 16; r++) oacc[n][r] *= al;
        }

        u32 pd[2][8];
#pragma unroll
        for (int n = 0; n < 2; n++)
#pragma unroll
            for (int m = 0; m < 8; m++) {
                float pa = __builtin_amdgcn_exp2f(s2[n][2 * m] - mrow);
                float pb = __builtin_amdgcn_exp2f(s2[n][2 * m + 1] - mrow);
                pd[n][m] = packbf2(pa, pb);
            }

        __builtin_amdgcn_s_setprio(1);
#pragma unroll
        for (int ks = 0; ks < 4; ks++) {
            const int n = ks >> 1, bb2 = ks & 1;
            union { u32 u[4]; short8 v; } pB;
            pB.u[0] = pd[n][4 * bb2 + 0];
            pB.u[1] = pd[n][4 * bb2 + 1];
            pB.u[2] = pd[n][4 * bb2 + 2];
            pB.u[3] = pd[n][4 * bb2 + 3];
            const int csl = (2 * ks + e) ^ csl_base;
#pragma unroll
            for (int n2 = 0; n2 < 3; n2++) {
                short8 vf = *(const short8*)(vb + ((n2 * 32 + l31) * 8 + csl) * 16);
                oacc[n2] = __builtin_amdgcn_mfma_f32_32x32x16_bf16(vf, pB.v, oacc[n2], 0, 0, 0);
            }
        }
        __builtin_amdgcn_s_setprio(0);

        __syncthreads();   // drains stage(kt+1) (issued a full iter ago: free)
        if (kt + 2 < NT) {
            stageK(kt + 2, kt & 1);
            stageV(kt + 2, kt & 1);
        }
    }

    if (e == 0) {
        int mi = kvs * 65536 + bh * Ss + q0 + w * 32 + l31;
        Mp[mi] = mrow;
        Lp[mi] = oacc[2][8];
    }

    u16* Ob = (u16*)smem;
#pragma unroll
    for (int n = 0; n < 3; n++)
#pragma unroll
        for (int r = 0; r < 16; r += 2) {
            if (n == 2 && r >= 8) continue;
            int dloc = n * 32 + (r & 3) + 8 * (r >> 2) + 4 * e;
            u32 pk = packbf2(oacc[n][r], oacc[n][r + 1]);
            *(u32*)&Ob[(w * 32 + l31) * OBP + dloc] = pk;
        }
    __syncthreads();

    u16* Np = kvs ? N1 : N0;
    const int cb = h * Dd;
#pragma unroll
    for (int i = 0; i < 5; i++) {
        int gidx = i * 256 + t;
        int row = gidx / 10, gi = gidx % 10;
        short8 v = *(const short8*)&Ob[row * OBP + gi * 8];
        *(short8*)(Np + (rowBase + q0 + row) * Cc + cb + gi * 8) = v;
    }
}

// ---------------------------------------------------------------------------
// Kernel D: O-projection + fused 2-way kv-split merge + bias + residual.
// ---------------------------------------------------------------------------
__global__ __launch_bounds__(256) void gemm_oproj(
    const u16* __restrict__ N0, const u16* __restrict__ N1,
    const u16* __restrict__ Bt,
    const float* __restrict__ Mp, const float* __restrict__ Lp,
    const float* __restrict__ bias, const float* __restrict__ resid,
    float* __restrict__ Out)
{
    __shared__ __align__(16) char osm[28672];
    float* WF = (float*)(osm + 24576);   // [64][8][2]

    const int mBase = blockIdx.x * 64;
    const int nBase = blockIdx.y * 128;
    const int t = threadIdx.x, lane = t & 63, w = t >> 6;
    const int wr = w >> 1, wc = w & 1;
    const int l15 = lane & 15, g = lane >> 4;

    for (int i = t; i < 512; i += 256) {
        int r = i >> 3, h = i & 7;
        int row = mBase + r;
        int bb = row >> 12, q = row & 4095;
        int mi = (bb * 8 + h) * Ss + q;
        float m0 = Mp[mi], m1 = Mp[65536 + mi];
        float l0 = Lp[mi], l1 = Lp[65536 + mi];
        float m = fmaxf(m0, m1);
        float w0 = exp2f(m0 - m), w1 = exp2f(m1 - m);
        float rl = 1.0f / (l0 * w0 + l1 * w1);
        WF[(r * 8 + h) * 2 + 0] = w0 * rl;
        WF[(r * 8 + h) * 2 + 1] = w1 * rl;
    }

    const int rA = t >> 2, clA = t & 3;
    const int cgA = clA ^ (rA & 3);
    const int rB0 = t >> 2, rB1 = (t + 256) >> 2;
    const int cgB0 = (t & 3) ^ (rB0 & 3);
    const int cgB1 = (t & 3) ^ (rB1 & 3);
    const u16* pA0 = N0 + (size_t)(mBase + rA) * Cc + cgA * 8;
    const u16* pA1 = N1 + (size_t)(mBase + rA) * Cc + cgA * 8;
    const u16* pB0 = Bt + (size_t)(nBase + rB0) * Cc + cgB0 * 8;
    const u16* pB1 = Bt + (size_t)(nBase + rB1) * Cc + cgB1 * 8;

    auto stageB = [&](int k0, int buf) {
        GLD16(pB0 + k0, osm + 8192 + buf * 8192 + w * 1024);
        GLD16(pB1 + k0, osm + 8192 + buf * 8192 + 4096 + w * 1024);
    };
    auto stageA = [&](int k0, int buf) {
        int kA = k0 + cgA * 8;
        int hA = kA / 80;
        float w0 = WF[(rA * 8 + hA) * 2], w1 = WF[(rA * 8 + hA) * 2 + 1];
        short8 a0 = *(const short8*)(pA0 + k0);
        short8 c0 = *(const short8*)(pA1 + k0);
        union { u32 u[4]; short8 v; } mg;
#pragma unroll
        for (int j = 0; j < 4; j++)
            mg.u[j] = packbf2(bf2f((u16)a0[2 * j]) * w0 + bf2f((u16)c0[2 * j]) * w1,
                              bf2f((u16)a0[2 * j + 1]) * w0 + bf2f((u16)c0[2 * j + 1]) * w1);
        *(short8*)(osm + buf * 4096 + rA * 64 + clA * 16) = mg.v;
    };

    __syncthreads();        // WF ready
    stageB(0, 0);
    stageA(0, 0);
    __syncthreads();

    f32x4 acc[2][4] = {};
    const int lof = l15 * 64 + ((g ^ (l15 & 3)) << 4);
    int cur = 0;

    for (int k0 = 0; k0 < Cc; k0 += 32) {
        const bool more = (k0 + 32 < Cc);
        if (more) stageB(k0 + 32, cur ^ 1);
        short8 af[2], bf[4];
#pragma unroll
        for (int i = 0; i < 2; i++)
            af[i] = *(const short8*)(osm + cur * 4096 + wr * 2048 + i * 1024 + lof);
#pragma unroll
        for (int i = 0; i < 4; i++)
            bf[i] = *(const short8*)(osm + 8192 + cur * 8192 + wc * 4096 + i * 1024 + lof);
#pragma unroll
        for (int mi = 0; mi < 2; mi++)
#pragma unroll
            for (int ni = 0; ni < 4; ni++)
                acc[mi][ni] = __builtin_amdgcn_mfma_f32_16x16x32_bf16(af[mi], bf[ni], acc[mi][ni], 0, 0, 0);
        if (more) stageA(k0 + 32, cur ^ 1);
        __syncthreads();
        cur ^= 1;
    }

#pragma unroll
    for (int mi = 0; mi < 2; mi++)
#pragma unroll
        for (int ni = 0; ni < 4; ni++) {
            int col = nBase + wc * 64 + ni * 16 + l15;
            float bb = bias[col];
#pragma unroll
            for (int r = 0; r < 4; r++) {
                int row = mBase + wr * 32 + mi * 16 + g * 4 + r;
                Out[(size_t)row * Cc + col] = acc[mi][ni][r] + bb + resid[(size_t)row * Cc + col];
            }
        }
}

// ---------------------------------------------------------------------------
extern "C" void kernel_launch(void* const* d_in, const int* in_sizes, int n_in,
                              void* d_out, int out_size, void* d_ws, size_t ws_size,
                              hipStream_t stream) {
    (void)in_sizes; (void)n_in; (void)out_size; (void)ws_size;
    const float* hs = (const float*)d_in[0];
    const float* Wq = (const float*)d_in[1];
    const float* bq = (const float*)d_in[2];
    const float* Wk = (const float*)d_in[3];
    const float* bk = (const float*)d_in[4];
    const float* Wv = (const float*)d_in[5];
    const float* bv = (const float*)d_in[6];
    const float* Wo = (const float*)d_in[7];
    const float* bo = (const float*)d_in[8];
    float* out = (float*)d_out;

    char* ws = (char*)d_ws;
    u16*   Xb    = (u16*)  (ws + 0);          // 10,485,760 (N1 after gemm_qkv)
    u16*   WTqkv = (u16*)  (ws + 10485760);   //  2,457,600
    u16*   WTo   = (u16*)  (ws + 12943360);   //    819,200
    float* bcat  = (float*)(ws + 13762560);   //      7,680
    u16*   QK    = (u16*)  (ws + 13770240);   // 20,971,520
    u16*   VTg   = (u16*)  (ws + 34741760);   // 10,485,760
    u16*   AOb   = (u16*)  (ws + 45227520);   // 10,485,760 (N0)
    float* Mp    = (float*)(ws + 55713280);   //    524,288
    float* Lp    = (float*)(ws + 56237568);   //    524,288
    u16*   N1    = Xb;                        // overlay: Xb dead after gemm_qkv

    prep_kernel<<<dim3(3648), dim3(256), 0, stream>>>(hs, Wq, Wk, Wv, Wo, bq, bk, bv,
                                                      Xb, bcat, WTqkv, WTo);
    gemm_qkv<<<dim3(64, 15), dim3(256), 0, stream>>>(Xb, WTqkv, bcat, QK, VTg);
    attn_kernel<<<dim3(1024), dim3(256), 0, stream>>>(QK, VTg, AOb, N1, Mp, Lp);
    gemm_oproj<<<dim3(128, 5), dim3(256), 0, stream>>>(AOb, N1, WTo, Mp, Lp, bo, hs, out);
}

// Round 22
// 167.339 us; speedup vs baseline: 1.0630x; 1.0630x over previous
//
#include <hip/hip_runtime.h>
#include <hip/hip_bf16.h>
#include <stdint.h>

typedef __attribute__((ext_vector_type(8))) short short8;
typedef __attribute__((ext_vector_type(4))) short short4v;
typedef __attribute__((ext_vector_type(4))) float f32x4;
typedef __attribute__((ext_vector_type(16))) float f32x16;
typedef unsigned short u16;
typedef unsigned int u32;

#define DEV __device__ __forceinline__

constexpr int Bb = 2, Ss = 4096, Cc = 640, Hh = 8, Dd = 80;
constexpr int BS = Bb * Ss;          // 8192
constexpr int NQKV = 3 * Cc;         // 1920
constexpr int QKst = 2 * Cc;         // 1280

DEV float bf2f(u16 u) { unsigned v = ((unsigned)u) << 16; float f; __builtin_memcpy(&f, &v, 4); return f; }
DEV u16 f2bf(float f) {
    unsigned u; __builtin_memcpy(&u, &f, 4);
    u += 0x7fffu + ((u >> 16) & 1u);
    return (u16)(u >> 16);
}
DEV u32 packbf2(float a, float b) {
    float2 f2; f2.x = a; f2.y = b;
    __hip_bfloat162 h2 = __float22bfloat162_rn(f2);
    u32 r; __builtin_memcpy(&r, &h2, 4);
    return r;
}

DEV void pswapf(float &a, float &b) {
#if __has_builtin(__builtin_amdgcn_permlane32_swap)
    auto r = __builtin_amdgcn_permlane32_swap(__float_as_int(a), __float_as_int(b), false, false);
    a = __int_as_float(r[0]); b = __int_as_float(r[1]);
#else
    float sa = __shfl_xor(a, 32, 64), sb = __shfl_xor(b, 32, 64);
    bool hi = (threadIdx.x & 32) != 0;
    float na = hi ? sb : a, nb = hi ? b : sa;
    a = na; b = nb;
#endif
}

#define GLD16(gp, lp) __builtin_amdgcn_global_load_lds( \
    (const __attribute__((address_space(1))) void*)(gp), \
    (__attribute__((address_space(3))) void*)(lp), 16, 0, 0)

// ---------------------------------------------------------------------------
// Kernel A (merged): blocks [0,1600): weight transpose; rest: hs->bf16 + bias.
// ---------------------------------------------------------------------------
__global__ __launch_bounds__(256) void prep_kernel(
    const float* __restrict__ hs,
    const float* __restrict__ Wq, const float* __restrict__ Wk,
    const float* __restrict__ Wv, const float* __restrict__ Wo,
    const float* __restrict__ bq, const float* __restrict__ bk,
    const float* __restrict__ bv,
    u16* __restrict__ Xb, float* __restrict__ bcat,
    u16* __restrict__ WTqkv, u16* __restrict__ WTo)
{
    const float QS = 0.11180339887498949f * 1.4426950408889634f;
    if (blockIdx.x < 1600) {
        __shared__ float T[32][33];
        int tile = blockIdx.x;
        int wsel = tile / 400;
        int tt = tile - wsel * 400;
        int tr = tt / 20, tc = tt - (tt / 20) * 20;
        const float* W = (wsel == 0) ? Wq : (wsel == 1) ? Wk : (wsel == 2) ? Wv : Wo;
        float sc = (wsel == 0) ? QS : 1.0f;
        int r = threadIdx.x >> 3, c4 = (threadIdx.x & 7) * 4;
        float4 v = *(const float4*)(W + (size_t)(tr * 32 + r) * Cc + tc * 32 + c4);
        T[r][c4 + 0] = v.x; T[r][c4 + 1] = v.y; T[r][c4 + 2] = v.z; T[r][c4 + 3] = v.w;
        __syncthreads();
        short4v o;
#pragma unroll
        for (int j = 0; j < 4; j++) o[j] = (short)f2bf(T[c4 + j][r] * sc);
        u16* dst = (wsel < 3) ? (WTqkv + (size_t)(wsel * Cc + tc * 32 + r) * Cc + tr * 32 + c4)
                              : (WTo + (size_t)(tc * 32 + r) * Cc + tr * 32 + c4);
        *(short4v*)dst = o;
    } else {
        int tid = (blockIdx.x - 1600) * blockDim.x + threadIdx.x;
        int nthr = 2048 * blockDim.x;
        for (int i = tid; i < BS * Cc / 4; i += nthr) {
            float4 v = ((const float4*)hs)[i];
            short4v o;
            o[0] = (short)f2bf(v.x); o[1] = (short)f2bf(v.y);
            o[2] = (short)f2bf(v.z); o[3] = (short)f2bf(v.w);
            ((short4v*)Xb)[i] = o;
        }
        for (int i = tid; i < NQKV; i += nthr) {
            float v = (i < Cc) ? bq[i] * QS : (i < 2 * Cc) ? bk[i - Cc] : bv[i - 2 * Cc];
            bcat[i] = v;
        }
    }
}

// ---------------------------------------------------------------------------
// Kernel B: QKV GEMM (m97-style staging). Q,K -> QK[row][1280]; V -> VTg
// transposed + kv bits 2<->3 pre-permuted.
// ---------------------------------------------------------------------------
__global__ __launch_bounds__(256) void gemm_qkv(
    const u16* __restrict__ A, const u16* __restrict__ Bt,
    const float* __restrict__ bias, u16* __restrict__ QK,
    u16* __restrict__ VTg)
{
    __shared__ __align__(16) char gsm[32768];

    const int mBase = blockIdx.x * 128;
    const int nBase = blockIdx.y * 128;
    const int t = threadIdx.x, lane = t & 63, w = t >> 6;
    const int wr = w >> 1, wc = w & 1;
    const int l15 = lane & 15, g = lane >> 4;

    const int r0 = t >> 2, r1 = (t + 256) >> 2;
    const int cg0 = (t & 3) ^ (r0 & 3);
    const int cg1 = (t & 3) ^ (r1 & 3);
    const u16* pa0 = A + (size_t)(mBase + r0) * Cc + cg0 * 8;
    const u16* pa1 = A + (size_t)(mBase + r1) * Cc + cg1 * 8;
    const u16* pb0 = Bt + (size_t)(nBase + r0) * Cc + cg0 * 8;
    const u16* pb1 = Bt + (size_t)(nBase + r1) * Cc + cg1 * 8;

    auto stage = [&](int k0, int buf) {
        GLD16(pa0 + k0, gsm + buf * 8192 + w * 1024);
        GLD16(pa1 + k0, gsm + buf * 8192 + 4096 + w * 1024);
        GLD16(pb0 + k0, gsm + 16384 + buf * 8192 + w * 1024);
        GLD16(pb1 + k0, gsm + 16384 + buf * 8192 + 4096 + w * 1024);
    };

    stage(0, 0);
    __syncthreads();

    f32x4 acc[4][4] = {};
    const int lof = l15 * 64 + ((g ^ (l15 & 3)) << 4);
    int cur = 0;

    for (int k0 = 0; k0 < Cc; k0 += 32) {
        if (k0 + 32 < Cc) stage(k0 + 32, cur ^ 1);
        short8 af[4], bf[4];
#pragma unroll
        for (int i = 0; i < 4; i++) {
            af[i] = *(const short8*)(gsm + cur * 8192 + wr * 4096 + i * 1024 + lof);
            bf[i] = *(const short8*)(gsm + 16384 + cur * 8192 + wc * 4096 + i * 1024 + lof);
        }
#pragma unroll
        for (int mi = 0; mi < 4; mi++)
#pragma unroll
            for (int ni = 0; ni < 4; ni++)
                acc[mi][ni] = __builtin_amdgcn_mfma_f32_16x16x32_bf16(af[mi], bf[ni], acc[mi][ni], 0, 0, 0);
        __syncthreads();
        cur ^= 1;
    }

    if (nBase < 2 * Cc) {
#pragma unroll
        for (int mi = 0; mi < 4; mi++)
#pragma unroll
            for (int ni = 0; ni < 4; ni++) {
                int col = nBase + wc * 64 + ni * 16 + l15;
                float bb = bias[col];
#pragma unroll
                for (int r = 0; r < 4; r++) {
                    int row = mBase + wr * 64 + mi * 16 + g * 4 + r;
                    QK[(size_t)row * QKst + col] = f2bf(acc[mi][ni][r] + bb);
                }
            }
    } else {
        const int gp = ((g & 1) << 1) | (g >> 1);   // kv bits 2<->3 swap
#pragma unroll
        for (int mi = 0; mi < 4; mi++)
#pragma unroll
            for (int ni = 0; ni < 4; ni++) {
                int colg = nBase + wc * 64 + ni * 16 + l15;   // 1280..1919
                float bb = bias[colg];
                int vc = colg - 2 * Cc;
                int h = vc / Dd, d = vc - h * Dd;
                int row0 = mBase + wr * 64 + mi * 16 + gp * 4;
                int b = (mBase >> 12), s = row0 & 4095;
                short4v o;
#pragma unroll
                for (int r = 0; r < 4; r++) o[r] = (short)f2bf(acc[mi][ni][r] + bb);
                *(short4v*)(VTg + ((size_t)(b * Hh + h) * Dd + d) * Ss + s) = o;
            }
    }
}

// ---------------------------------------------------------------------------
// Kernel C: flash attention — R16 deep-prefetch schedule with 8-WAVE BLOCKS
// (256 q-rows/block). Grid 512 = EXACTLY 2 blocks/CU resident for the whole
// kernel = 16 waves/CU flat, vs R16-R21's ragged 12-then-4 (avg 8.1, measured
// Occupancy 25.4%). Same per-wave work (32 q-rows), same VGPR-72 structure,
// K/V staged once per 256 q (half the stage traffic). LDS 45056 = 2 x
// {K [10][64][16B], V [96][8][16B] ones rows 80..95}; Ob overlay [256][88]
// fits exactly. Stage map: wave w covers chunks {w, w+8} (w<2 gets 2).
// ---------------------------------------------------------------------------
constexpr int OBP = 88;

__global__ __launch_bounds__(512, 4) void attn_kernel(
    const u16* __restrict__ QK, const u16* __restrict__ VTg,
    u16* __restrict__ N0, u16* __restrict__ N1,
    float* __restrict__ Mp, float* __restrict__ Lp)
{
    __shared__ __align__(16) char smem[45056];

    const int id = blockIdx.x;          // 0..511
    const int qt = id >> 5;             // 0..15
    const int bh = (id & 31) >> 1;
    const int kvs = id & 1;
    const int b = bh >> 3, h = bh & 7;
    const int t = threadIdx.x, lane = t & 63, w = t >> 6;   // w: 0..7
    const int l31 = lane & 31, e = lane >> 5;

    const size_t rowBase = (size_t)b * Ss;
    const int q0 = qt * 256;
    const int kvBase = kvs * (Ss / 2);
    constexpr int NT = (Ss / 2) / 64;   // 32

    const int lq8 = lane >> 3;
    const int vcg = (lane & 7) ^ lq8;
    const u16* kg0 = QK + (rowBase + kvBase + lane) * QKst + Cc + h * Dd;
    const u16* vg0 = VTg + ((size_t)bh * Dd) * Ss + kvBase + vcg * 8;

    // ones rows 80..95 of BOTH V buffers (l-via-MFMA); stageV writes rows
    // 0..79 only, so these persist. 512 u32 per buffer, one per thread.
    ((u32*)(smem + 10240 + 80 * 128))[t] = 0x3F803F80u;
    ((u32*)(smem + 22528 + 10240 + 80 * 128))[t] = 0x3F803F80u;

    short8 qB[5];
    {
        const u16* qp = QK + (rowBase + q0 + w * 32 + l31) * QKst + h * Dd + e * 8;
#pragma unroll
        for (int ks = 0; ks < 5; ks++) qB[ks] = *(const short8*)(qp + ks * 16);
    }

    auto stageK = [&](int kt, int buf) {
#pragma unroll
        for (int j = 0; j < 2; j++) {
            int gi = w + 8 * j;
            if (gi < 10)
                GLD16(kg0 + (size_t)kt * 64 * QKst + gi * 8,
                      smem + buf * 22528 + gi * 1024);
        }
    };
    auto stageV = [&](int kt, int buf) {
#pragma unroll
        for (int j = 0; j < 2; j++) {
            int gi = w + 8 * j;
            if (gi < 10)
                GLD16(vg0 + (size_t)(gi * 8 + lq8) * Ss + kt * 64,
                      smem + buf * 22528 + 10240 + gi * 1024);
        }
    };

    stageK(0, 0);
    stageV(0, 0);
    stageK(1, 1);
    stageV(1, 1);
    __syncthreads();   // tiles 0,1 + ones rows in LDS

    float mrow = -1e30f;
    f32x16 oacc[3] = {};
    const int csl_base = l31 & 7;

    for (int kt = 0; kt < NT; ++kt) {
        const char* kb = smem + (kt & 1) * 22528;
        const char* vb = kb + 10240;

        // S^T = K Q^T
        f32x16 s2[2];
        __builtin_amdgcn_s_setprio(1);
#pragma unroll
        for (int n = 0; n < 2; n++) {
            f32x16 a = {};
#pragma unroll
            for (int ks = 0; ks < 5; ks++) {
                short8 kf = *(const short8*)(kb + ((2 * ks + e) * 64 + n * 32 + l31) * 16);
                a = __builtin_amdgcn_mfma_f32_32x32x16_bf16(kf, qB[ks], a, 0, 0, 0);
            }
            s2[n] = a;
        }
        __builtin_amdgcn_s_setprio(0);

#define SV(j) ((j) < 16 ? s2[0][(j)] : s2[1][(j) - 16])
        float tt[11];
#pragma unroll
        for (int i = 0; i < 10; i++)
            tt[i] = fmaxf(fmaxf(SV(3 * i), SV(3 * i + 1)), SV(3 * i + 2));
        tt[10] = fmaxf(SV(30), SV(31));
#undef SV
        float u0 = fmaxf(fmaxf(tt[0], tt[1]), tt[2]);
        float u1 = fmaxf(fmaxf(tt[3], tt[4]), tt[5]);
        float u2 = fmaxf(fmaxf(tt[6], tt[7]), tt[8]);
        float u3 = fmaxf(tt[9], tt[10]);
        float vm = fmaxf(fmaxf(u0, u1), fmaxf(u2, u3));
        { float va = vm, vb2 = vm; pswapf(va, vb2); vm = fmaxf(va, vb2); }

        if (__any(vm > mrow + 8.0f)) {   // defer-max; l rescales inside oacc[2]
            float mnew = fmaxf(mrow, vm);
            float al = __builtin_amdgcn_exp2f(mrow - mnew);
            mrow = mnew;
#pragma unroll
            for (int n = 0; n < 3; n++)
#pragma unroll
                for (int r = 0; r < 16; r++) oacc[n][r] *= al;
        }

        u32 pd[2][8];
#pragma unroll
        for (int n = 0; n < 2; n++)
#pragma unroll
            for (int m = 0; m < 8; m++) {
                float pa = __builtin_amdgcn_exp2f(s2[n][2 * m] - mrow);
                float pb = __builtin_amdgcn_exp2f(s2[n][2 * m + 1] - mrow);
                pd[n][m] = packbf2(pa, pb);
            }

        // PV (V pre-permuted -> pd direct); rows 80..95 ones -> l
        __builtin_amdgcn_s_setprio(1);
#pragma unroll
        for (int ks = 0; ks < 4; ks++) {
            const int n = ks >> 1, bb2 = ks & 1;
            union { u32 u[4]; short8 v; } pB;
            pB.u[0] = pd[n][4 * bb2 + 0];
            pB.u[1] = pd[n][4 * bb2 + 1];
            pB.u[2] = pd[n][4 * bb2 + 2];
            pB.u[3] = pd[n][4 * bb2 + 3];
            const int csl = (2 * ks + e) ^ csl_base;
#pragma unroll
            for (int n2 = 0; n2 < 3; n2++) {
                short8 vf = *(const short8*)(vb + ((n2 * 32 + l31) * 8 + csl) * 16);
                oacc[n2] = __builtin_amdgcn_mfma_f32_32x32x16_bf16(vf, pB.v, oacc[n2], 0, 0, 0);
            }
        }
        __builtin_amdgcn_s_setprio(0);

        __syncthreads();   // drains stage(kt+1) (issued a full iter ago: free)
        if (kt + 2 < NT) {
            stageK(kt + 2, kt & 1);
            stageV(kt + 2, kt & 1);
        }
    }

    if (e == 0) {
        int mi = kvs * 65536 + bh * Ss + q0 + w * 32 + l31;
        Mp[mi] = mrow;
        Lp[mi] = oacc[2][8];
    }

    // pack numerator O^T -> Ob overlay ([256][88] = 45056 B exactly)
    u16* Ob = (u16*)smem;
#pragma unroll
    for (int n = 0; n < 3; n++)
#pragma unroll
        for (int r = 0; r < 16; r += 2) {
            if (n == 2 && r >= 8) continue;
            int dloc = n * 32 + (r & 3) + 8 * (r >> 2) + 4 * e;
            u32 pk = packbf2(oacc[n][r], oacc[n][r + 1]);
            *(u32*)&Ob[(w * 32 + l31) * OBP + dloc] = pk;
        }
    __syncthreads();

    u16* Np = kvs ? N1 : N0;
    const int cb = h * Dd;
#pragma unroll
    for (int i = 0; i < 5; i++) {
        int gidx = i * 512 + t;                 // 0..2559
        int row = gidx / 10, gi = gidx % 10;
        short8 v = *(const short8*)&Ob[row * OBP + gi * 8];
        *(short8*)(Np + (rowBase + q0 + row) * Cc + cb + gi * 8) = v;
    }
}

// ---------------------------------------------------------------------------
// Kernel D: O-projection + fused 2-way kv-split merge + bias + residual.
// ---------------------------------------------------------------------------
__global__ __launch_bounds__(256) void gemm_oproj(
    const u16* __restrict__ N0, const u16* __restrict__ N1,
    const u16* __restrict__ Bt,
    const float* __restrict__ Mp, const float* __restrict__ Lp,
    const float* __restrict__ bias, const float* __restrict__ resid,
    float* __restrict__ Out)
{
    __shared__ __align__(16) char osm[28672];
    float* WF = (float*)(osm + 24576);   // [64][8][2]

    const int mBase = blockIdx.x * 64;
    const int nBase = blockIdx.y * 128;
    const int t = threadIdx.x, lane = t & 63, w = t >> 6;
    const int wr = w >> 1, wc = w & 1;
    const int l15 = lane & 15, g = lane >> 4;

    for (int i = t; i < 512; i += 256) {
        int r = i >> 3, h = i & 7;
        int row = mBase + r;
        int bb = row >> 12, q = row & 4095;
        int mi = (bb * 8 + h) * Ss + q;
        float m0 = Mp[mi], m1 = Mp[65536 + mi];
        float l0 = Lp[mi], l1 = Lp[65536 + mi];
        float m = fmaxf(m0, m1);
        float w0 = exp2f(m0 - m), w1 = exp2f(m1 - m);
        float rl = 1.0f / (l0 * w0 + l1 * w1);
        WF[(r * 8 + h) * 2 + 0] = w0 * rl;
        WF[(r * 8 + h) * 2 + 1] = w1 * rl;
    }

    const int rA = t >> 2, clA = t & 3;
    const int cgA = clA ^ (rA & 3);
    const int rB0 = t >> 2, rB1 = (t + 256) >> 2;
    const int cgB0 = (t & 3) ^ (rB0 & 3);
    const int cgB1 = (t & 3) ^ (rB1 & 3);
    const u16* pA0 = N0 + (size_t)(mBase + rA) * Cc + cgA * 8;
    const u16* pA1 = N1 + (size_t)(mBase + rA) * Cc + cgA * 8;
    const u16* pB0 = Bt + (size_t)(nBase + rB0) * Cc + cgB0 * 8;
    const u16* pB1 = Bt + (size_t)(nBase + rB1) * Cc + cgB1 * 8;

    auto stageB = [&](int k0, int buf) {
        GLD16(pB0 + k0, osm + 8192 + buf * 8192 + w * 1024);
        GLD16(pB1 + k0, osm + 8192 + buf * 8192 + 4096 + w * 1024);
    };
    auto stageA = [&](int k0, int buf) {
        int kA = k0 + cgA * 8;
        int hA = kA / 80;
        float w0 = WF[(rA * 8 + hA) * 2], w1 = WF[(rA * 8 + hA) * 2 + 1];
        short8 a0 = *(const short8*)(pA0 + k0);
        short8 c0 = *(const short8*)(pA1 + k0);
        union { u32 u[4]; short8 v; } mg;
#pragma unroll
        for (int j = 0; j < 4; j++)
            mg.u[j] = packbf2(bf2f((u16)a0[2 * j]) * w0 + bf2f((u16)c0[2 * j]) * w1,
                              bf2f((u16)a0[2 * j + 1]) * w0 + bf2f((u16)c0[2 * j + 1]) * w1);
        *(short8*)(osm + buf * 4096 + rA * 64 + clA * 16) = mg.v;
    };

    __syncthreads();        // WF ready
    stageB(0, 0);
    stageA(0, 0);
    __syncthreads();

    f32x4 acc[2][4] = {};
    const int lof = l15 * 64 + ((g ^ (l15 & 3)) << 4);
    int cur = 0;

    for (int k0 = 0; k0 < Cc; k0 += 32) {
        const bool more = (k0 + 32 < Cc);
        if (more) stageB(k0 + 32, cur ^ 1);
        short8 af[2], bf[4];
#pragma unroll
        for (int i = 0; i < 2; i++)
            af[i] = *(const short8*)(osm + cur * 4096 + wr * 2048 + i * 1024 + lof);
#pragma unroll
        for (int i = 0; i < 4; i++)
            bf[i] = *(const short8*)(osm + 8192 + cur * 8192 + wc * 4096 + i * 1024 + lof);
#pragma unroll
        for (int mi = 0; mi < 2; mi++)
#pragma unroll
            for (int ni = 0; ni < 4; ni++)
                acc[mi][ni] = __builtin_amdgcn_mfma_f32_16x16x32_bf16(af[mi], bf[ni], acc[mi][ni], 0, 0, 0);
        if (more) stageA(k0 + 32, cur ^ 1);
        __syncthreads();
        cur ^= 1;
    }

#pragma unroll
    for (int mi = 0; mi < 2; mi++)
#pragma unroll
        for (int ni = 0; ni < 4; ni++) {
            int col = nBase + wc * 64 + ni * 16 + l15;
            float bb = bias[col];
#pragma unroll
            for (int r = 0; r < 4; r++) {
                int row = mBase + wr * 32 + mi * 16 + g * 4 + r;
                Out[(size_t)row * Cc + col] = acc[mi][ni][r] + bb + resid[(size_t)row * Cc + col];
            }
        }
}

// ---------------------------------------------------------------------------
extern "C" void kernel_launch(void* const* d_in, const int* in_sizes, int n_in,
                              void* d_out, int out_size, void* d_ws, size_t ws_size,
                              hipStream_t stream) {
    (void)in_sizes; (void)n_in; (void)out_size; (void)ws_size;
    const float* hs = (const float*)d_in[0];
    const float* Wq = (const float*)d_in[1];
    const float* bq = (const float*)d_in[2];
    const float* Wk = (const float*)d_in[3];
    const float* bk = (const float*)d_in[4];
    const float* Wv = (const float*)d_in[5];
    const float* bv = (const float*)d_in[6];
    const float* Wo = (const float*)d_in[7];
    const float* bo = (const float*)d_in[8];
    float* out = (float*)d_out;

    char* ws = (char*)d_ws;
    u16*   Xb    = (u16*)  (ws + 0);          // 10,485,760 (N1 after gemm_qkv)
    u16*   WTqkv = (u16*)  (ws + 10485760);   //  2,457,600
    u16*   WTo   = (u16*)  (ws + 12943360);   //    819,200
    float* bcat  = (float*)(ws + 13762560);   //      7,680
    u16*   QK    = (u16*)  (ws + 13770240);   // 20,971,520
    u16*   VTg   = (u16*)  (ws + 34741760);   // 10,485,760
    u16*   AOb   = (u16*)  (ws + 45227520);   // 10,485,760 (N0)
    float* Mp    = (float*)(ws + 55713280);   //    524,288
    float* Lp    = (float*)(ws + 56237568);   //    524,288
    u16*   N1    = Xb;                        // overlay: Xb dead after gemm_qkv

    prep_kernel<<<dim3(3648), dim3(256), 0, stream>>>(hs, Wq, Wk, Wv, Wo, bq, bk, bv,
                                                      Xb, bcat, WTqkv, WTo);
    gemm_qkv<<<dim3(64, 15), dim3(256), 0, stream>>>(Xb, WTqkv, bcat, QK, VTg);
    attn_kernel<<<dim3(512), dim3(512), 0, stream>>>(QK, VTg, AOb, N1, Mp, Lp);
    gemm_oproj<<<dim3(128, 5), dim3(256), 0, stream>>>(AOb, N1, WTo, Mp, Lp, bo, hs, out);
}